// Round 15
// baseline (968.655 us; speedup 1.0000x reference)
//
#include <hip/hip_runtime.h>

#define NN 50000
#define NE 800000
#define NG 32
#define HID 128
#define BNEPS 1e-5f
#define NETOT (NE + NN)  // 850000, CSR total incl self loops

typedef float f32x2 __attribute__((ext_vector_type(2)));
typedef float f32x4 __attribute__((ext_vector_type(4)));
typedef short bf16x8 __attribute__((ext_vector_type(8)));

__device__ __forceinline__ unsigned fenc(float f) {
  unsigned u = __float_as_uint(f);
  return (u & 0x80000000u) ? ~u : (u | 0x80000000u);
}

__device__ __forceinline__ unsigned bfr(float f) {
  unsigned u = __float_as_uint(f);
  return (u + 0x7fffu + ((u >> 16) & 1u)) >> 16;
}
__device__ __forceinline__ unsigned pack2(float a, float b) {
  return bfr(a) | (bfr(b) << 16);
}
__device__ __forceinline__ float bf_lo(unsigned u) { return __uint_as_float(u << 16); }
__device__ __forceinline__ float bf_hi(unsigned u) { return __uint_as_float(u & 0xffff0000u); }

#define DPPADD(x, ctrl, rmask)                                                   \
  (x) += __int_as_float(__builtin_amdgcn_update_dpp(0, __float_as_int(x),        \
                                                    (ctrl), (rmask), 0xf, true))

// ---------------- preprocessing ----------------

__global__ __launch_bounds__(256) void k_hist(const int* __restrict__ ei,
                                              int* __restrict__ deg,
                                              int* __restrict__ pos) {
  int e = blockIdx.x * 256 + threadIdx.x;
  if (e >= NE) return;
  pos[e] = atomicAdd(&deg[ei[NE + e]], 1);
}

// ---- degree sort: two-level histogram (LDS first) to avoid atomic contention ----

__global__ __launch_bounds__(1024) void k_dhist(const int* __restrict__ deg,
                                                int* __restrict__ dhist) {
  __shared__ int lh[1024];
  int t = threadIdx.x;
  lh[t] = 0;
  __syncthreads();
  int n = blockIdx.x * 1024 + t;
  if (n < NN) atomicAdd(&lh[min(deg[n], 1023)], 1);
  __syncthreads();
  if (lh[t]) atomicAdd(&dhist[t], lh[t]);
}

__global__ __launch_bounds__(1024) void k_dscan(const int* __restrict__ dhist,
                                                int* __restrict__ dbase) {
  __shared__ int wsum[16];
  int t = threadIdx.x, lane = t & 63, w = t >> 6;
  int v = dhist[t];
  int s = v;
#pragma unroll
  for (int off = 1; off < 64; off <<= 1) {
    int y = __shfl_up(s, off, 64);
    if (lane >= off) s += y;
  }
  if (lane == 63) wsum[w] = s;
  __syncthreads();
  if (t < 16) {
    int xv = wsum[t];
#pragma unroll
    for (int off = 1; off < 16; off <<= 1) {
      int y = __shfl_up(xv, off, 64);
      if (t >= off) xv += y;
    }
    wsum[t] = xv;
  }
  __syncthreads();
  int incl = s + ((w == 0) ? 0 : wsum[w - 1]);
  dbase[t] = NN - incl;  // descending-degree base
}

__global__ __launch_bounds__(1024) void k_dscatter(const int* __restrict__ deg,
    const int* __restrict__ dbase, int* __restrict__ dfill,
    int* __restrict__ ord, int* __restrict__ rank) {
  __shared__ int lh[1024];
  __shared__ int lbase[1024];
  int t = threadIdx.x;
  lh[t] = 0;
  __syncthreads();
  int n = blockIdx.x * 1024 + t;
  int d = 0, lp = 0;
  if (n < NN) {
    d = min(deg[n], 1023);
    lp = atomicAdd(&lh[d], 1);  // local position within block's degree bucket
  }
  __syncthreads();
  if (lh[t]) lbase[t] = atomicAdd(&dfill[t], lh[t]);  // block base per degree
  __syncthreads();
  if (n < NN) {
    int p = dbase[d] + lbase[d] + lp;
    ord[p] = n;
    rank[n] = p;
  }
}

// hierarchical scan over SORTED degree order
__global__ __launch_bounds__(1024) void k_scanA(const int* __restrict__ deg,
                                                const int* __restrict__ ord,
                                                int* __restrict__ rowp,
                                                int* __restrict__ bsum) {
  __shared__ int wsum[16];
  int t = threadIdx.x, lane = t & 63, w = t >> 6;
  int i = blockIdx.x * 1024 + t;
  int v = (i < NN) ? (deg[ord[i]] + 1) : 0;  // +1 self loop
  int s = v;
#pragma unroll
  for (int off = 1; off < 64; off <<= 1) {
    int y = __shfl_up(s, off, 64);
    if (lane >= off) s += y;
  }
  if (lane == 63) wsum[w] = s;
  __syncthreads();
  if (t < 16) {
    int xv = wsum[t];
#pragma unroll
    for (int off = 1; off < 16; off <<= 1) {
      int y = __shfl_up(xv, off, 64);
      if (t >= off) xv += y;
    }
    wsum[t] = xv;
  }
  __syncthreads();
  int wexcl = (w == 0) ? 0 : wsum[w - 1];
  int incl = wexcl + s;
  if (i < NN) rowp[i] = incl - v;  // block-local exclusive
  if (t == 1023) bsum[blockIdx.x] = incl;
}

__global__ __launch_bounds__(64) void k_scanB(int* __restrict__ bsum,
                                              int* __restrict__ rowp,
                                              uint2* __restrict__ edat) {
  int t = threadIdx.x;  // one wave; 49 block sums
  int v = (t < 49) ? bsum[t] : 0;
  int s = v;
#pragma unroll
  for (int off = 1; off < 64; off <<= 1) {
    int y = __shfl_up(s, off, 64);
    if (t >= off) s += y;
  }
  bsum[t] = s - v;                 // exclusive
  if (t == 48) rowp[NN] = s;       // total (== NETOT)
  for (int j = t; j < 256; j += 64) {  // zero pad entries (clamp-free prefetch)
    uint2 z; z.x = 0u; z.y = 0u;
    edat[NETOT + j] = z;
  }
}

__global__ __launch_bounds__(1024) void k_scanC(int* __restrict__ rowp,
                                                const int* __restrict__ bsum) {
  int i = blockIdx.x * 1024 + threadIdx.x;
  if (i < NN) rowp[i] += bsum[blockIdx.x];
}

// scatter edges into SORTED dst-CSR order (atomic-free)
__global__ __launch_bounds__(256) void k_scatter(const int* __restrict__ ei,
    const float* __restrict__ eattr, const int* __restrict__ rowp,
    const int* __restrict__ pos, const int* __restrict__ rank,
    uint2* __restrict__ edat) {
  int e = blockIdx.x * 256 + threadIdx.x;
  if (e >= NE) return;
  int d = ei[NE + e];
  int p = rowp[rank[d]] + pos[e];
  uint2 v;
  v.x = (unsigned)ei[e] | (bfr(eattr[e * 3 + 0]) << 16);
  v.y = bfr(eattr[e * 3 + 1]) | (bfr(eattr[e * 3 + 2]) << 16);
  edat[p] = v;
}

// self-loop entry: mean of incoming edge attrs. one THREAD per sorted node.
__global__ __launch_bounds__(256) void k_selfmean(const int* __restrict__ rowp,
                                                  const int* __restrict__ ord,
                                                  uint2* __restrict__ edat) {
  int n = blockIdx.x * 256 + threadIdx.x;
  if (n >= NN) return;
  int beg = rowp[n], endm1 = rowp[n + 1] - 1;
  float s0 = 0.f, s1 = 0.f, s2 = 0.f;
  for (int i = beg; i < endm1; ++i) {
    uint2 v = edat[i];
    s0 += bf_hi(v.x); s1 += bf_lo(v.y); s2 += bf_hi(v.y);
  }
  int cnt = endm1 - beg;
  float inv = cnt > 0 ? 1.f / (float)cnt : 0.f;
  uint2 o;
  o.x = (unsigned)ord[n] | (bfr(s0 * inv) << 16);
  o.y = bfr(s1 * inv) | (bfr(s2 * inv) << 16);
  edat[endm1] = o;
}

// ---------------- layer 0 input transform ----------------

__global__ __launch_bounds__(256) void k_xform0(const float* __restrict__ x,
    const float* __restrict__ W0l, const float* __restrict__ W0r,
    unsigned* __restrict__ A, unsigned* __restrict__ B) {
  int t = blockIdx.x * 256 + threadIdx.x;
  int n = t >> 5;
  int c = (t & 31) * 4;
  if (n >= NN) return;
  float x0 = x[n * 3 + 0], x1 = x[n * 3 + 1], x2 = x[n * 3 + 2];
  float4 a0 = *(const float4*)&W0l[c];
  float4 a1 = *(const float4*)&W0l[HID + c];
  float4 a2 = *(const float4*)&W0l[2 * HID + c];
  float oax = x0 * a0.x + x1 * a1.x + x2 * a2.x;
  float oay = x0 * a0.y + x1 * a1.y + x2 * a2.y;
  float oaz = x0 * a0.z + x1 * a1.z + x2 * a2.z;
  float oaw = x0 * a0.w + x1 * a1.w + x2 * a2.w;
  uint2 pa;
  pa.x = pack2(oax, oay);
  pa.y = pack2(oaz, oaw);
  *(uint2*)&A[n * 64 + (c >> 1)] = pa;
  float4 b0 = *(const float4*)&W0r[c];
  float4 b1 = *(const float4*)&W0r[HID + c];
  float4 b2 = *(const float4*)&W0r[2 * HID + c];
  float obx = x0 * b0.x + x1 * b1.x + x2 * b2.x;
  float oby = x0 * b0.y + x1 * b1.y + x2 * b2.y;
  float obz = x0 * b0.z + x1 * b1.z + x2 * b2.z;
  float obw = x0 * b0.w + x1 * b1.w + x2 * b2.w;
  uint2 pb;
  pb.x = pack2(obx, oby);
  pb.y = pack2(obz, obw);
  *(uint2*)&B[n * 64 + (c >> 1)] = pb;
}

// ---------------- weight prep ----------------

__global__ __launch_bounds__(256) void k_wprep(const float* __restrict__ W,
    const float* __restrict__ cs, const float* __restrict__ g,
    const float* __restrict__ b, unsigned* __restrict__ Wt,
    float* __restrict__ bias2) {
  __shared__ float scS[HID], shS[HID];
  int t = threadIdx.x;
  if (t < HID) {
    float mu = cs[t] * (1.f / NN);
    float var = fmaxf(cs[HID + t] * (1.f / NN) - mu * mu, 0.f);
    float sc = g[t] * rsqrtf(var + BNEPS);
    scS[t] = sc;
    shS[t] = b[t] - mu * sc;
  }
  __syncthreads();
  for (int i = t; i < HID * 64; i += 256) {
    int n = i >> 6, kp = (i & 63) * 2;
    Wt[i] = pack2(scS[kp] * W[kp * HID + n], scS[kp + 1] * W[(kp + 1) * HID + n]);
  }
  if (t < HID) {
    float acc = 0.f;
    for (int k = 0; k < HID; ++k) acc += shS[k] * W[k * HID + t];
    bias2[t] = acc;
  }
}

// ---------------- GEMM (MFMA), 2 tiles per block ----------------

__global__ __launch_bounds__(256) void k_gemm(const unsigned* __restrict__ Hb,
    const unsigned* __restrict__ Wt, const float* __restrict__ bias2,
    unsigned* __restrict__ A) {
  __shared__ unsigned WsL[HID * 68];  // [128][68] pad, 34.8KB
  int t = threadIdx.x;
  for (int i4 = t * 4; i4 < HID * 64; i4 += 1024) {
    uint4 v = *(const uint4*)&Wt[i4];
    *(uint4*)&WsL[(i4 >> 6) * 68 + (i4 & 63)] = v;
  }
  __syncthreads();
  int l = t & 63;
  int w = t >> 6;
  int l15 = l & 15;
  int kg = (l >> 4) * 4;
  float bl[8];
#pragma unroll
  for (int nt = 0; nt < 8; ++nt) bl[nt] = bias2[nt * 16 + l15];
  for (int rb = blockIdx.x; rb * 64 < NN; rb += gridDim.x) {
    int r0 = rb * 64 + w * 16;
    int arow = min(r0 + l15, NN - 1);
    f32x4 acc[8] = {};
#pragma unroll
    for (int ks = 0; ks < 4; ++ks) {
      uint4 au = *(const uint4*)&Hb[arow * 64 + ks * 16 + kg];
      au.x &= ~(((au.x >> 15) & 0x10001u) * 0xFFFFu);  // packed relu
      au.y &= ~(((au.y >> 15) & 0x10001u) * 0xFFFFu);
      au.z &= ~(((au.z >> 15) & 0x10001u) * 0xFFFFu);
      au.w &= ~(((au.w >> 15) & 0x10001u) * 0xFFFFu);
      bf16x8 af = *(bf16x8*)&au;
#pragma unroll
      for (int nt = 0; nt < 8; ++nt) {
        uint4 bu = *(const uint4*)&WsL[(nt * 16 + l15) * 68 + ks * 16 + kg];
        bf16x8 bf = *(bf16x8*)&bu;
        acc[nt] = __builtin_amdgcn_mfma_f32_16x16x32_bf16(af, bf, acc[nt], 0, 0, 0);
      }
    }
#pragma unroll
    for (int nt = 0; nt < 8; ++nt) {
#pragma unroll
      for (int reg = 0; reg < 4; ++reg) {
        float v = acc[nt][reg] + bl[nt];
        float nb = __shfl_down(v, 1, 64);
        int rm = r0 + (l >> 4) * 4 + reg;
        if (((l & 1) == 0) && rm < NN)
          A[rm * 64 + nt * 8 + (l15 >> 1)] = pack2(v, nb);
      }
    }
  }
}

// ---- GATv2 edge phase v11: sorted nodes, 4 dst/wave, 2 live gather buffers
//      (VGPR <= 64 for 8 waves/SIMD), row_ror DPP allreduce, padded edat ----

__global__ __launch_bounds__(256, 8) void k_edge(const unsigned* __restrict__ XL,
    const unsigned* __restrict__ XR, const uint2* __restrict__ edat,
    const int* __restrict__ rowp, const int* __restrict__ ord,
    const float* __restrict__ We, const float* __restrict__ att,
    const float* __restrict__ bias, unsigned* __restrict__ Hb) {
  __shared__ float WeS[3 * HID];
  int t = threadIdx.x;
  for (int i = t; i < 3 * HID; i += 256) WeS[i] = We[i];
  __syncthreads();
  int lane = t & 63;
  int l4 = lane & 15;
  int n = blockIdx.x * 16 + (t >> 6) * 4 + (lane >> 4);  // sorted slot
  int orig = ord[n];
  int c0 = l4 * 8;
  uint4 urx = *(const uint4*)&XR[orig * 64 + l4 * 4];
  f32x2 xr0 = {bf_lo(urx.x), bf_hi(urx.x)};
  f32x2 xr1 = {bf_lo(urx.y), bf_hi(urx.y)};
  f32x2 xr2 = {bf_lo(urx.z), bf_hi(urx.z)};
  f32x2 xr3 = {bf_lo(urx.w), bf_hi(urx.w)};
  f32x2 at0 = *(const f32x2*)&att[c0];
  f32x2 at1 = *(const f32x2*)&att[c0 + 2];
  f32x2 at2 = *(const f32x2*)&att[c0 + 4];
  f32x2 at3 = *(const f32x2*)&att[c0 + 6];
  at0 *= 1.44269504f; at1 *= 1.44269504f; at2 *= 1.44269504f; at3 *= 1.44269504f;
  f32x2 w00 = *(const f32x2*)&WeS[c0],         w01 = *(const f32x2*)&WeS[c0 + 2];
  f32x2 w02 = *(const f32x2*)&WeS[c0 + 4],     w03 = *(const f32x2*)&WeS[c0 + 6];
  f32x2 w10 = *(const f32x2*)&WeS[HID + c0],   w11 = *(const f32x2*)&WeS[HID + c0 + 2];
  f32x2 w12 = *(const f32x2*)&WeS[HID + c0+4], w13 = *(const f32x2*)&WeS[HID + c0 + 6];
  f32x2 w20 = *(const f32x2*)&WeS[2*HID + c0],   w21 = *(const f32x2*)&WeS[2*HID + c0 + 2];
  f32x2 w22 = *(const f32x2*)&WeS[2*HID + c0+4], w23 = *(const f32x2*)&WeS[2*HID + c0 + 6];
  int beg = rowp[n], end = rowp[n + 1];
  int rem = end - beg;
  int tc = rem;
  tc = max(tc, __shfl_xor(tc, 16, 64));
  tc = max(tc, __shfl_xor(tc, 32, 64));
  int trips = (__builtin_amdgcn_readfirstlane(tc) + 3) & ~3;
  const unsigned* XLg = XL + l4 * 4;

  uint2 e0 = edat[beg], e1 = edat[beg + 1], e2 = edat[beg + 2], e3 = edat[beg + 3];
  uint4 x0 = *(const uint4*)&XLg[(e0.x & 0xffffu) * 64];
  uint4 x1;
  f32x2 a0 = {0.f, 0.f}, a1 = {0.f, 0.f}, a2 = {0.f, 0.f}, a3 = {0.f, 0.f};
  float s = 0.f;

#define BODY(ED, XU, J)                                                           \
  {                                                                               \
    f32x2 xs0 = {bf_lo(XU.x), bf_hi(XU.x)};                                       \
    f32x2 xs1 = {bf_lo(XU.y), bf_hi(XU.y)};                                       \
    f32x2 xs2 = {bf_lo(XU.z), bf_hi(XU.z)};                                       \
    f32x2 xs3 = {bf_lo(XU.w), bf_hi(XU.w)};                                       \
    float ea0 = bf_hi(ED.x), ea1 = bf_lo(ED.y), ea2 = bf_hi(ED.y);                \
    f32x2 u0 = xs0 + xr0, u1 = xs1 + xr1, u2 = xs2 + xr2, u3 = xs3 + xr3;         \
    u0 = ea0 * w00 + u0; u1 = ea0 * w01 + u1; u2 = ea0 * w02 + u2; u3 = ea0 * w03 + u3; \
    u0 = ea1 * w10 + u0; u1 = ea1 * w11 + u1; u2 = ea1 * w12 + u2; u3 = ea1 * w13 + u3; \
    u0 = ea2 * w20 + u0; u1 = ea2 * w21 + u1; u2 = ea2 * w22 + u2; u3 = ea2 * w23 + u3; \
    f32x2 v0 = __builtin_elementwise_max(u0, 0.2f * u0);                          \
    f32x2 v1 = __builtin_elementwise_max(u1, 0.2f * u1);                          \
    f32x2 v2 = __builtin_elementwise_max(u2, 0.2f * u2);                          \
    f32x2 v3 = __builtin_elementwise_max(u3, 0.2f * u3);                          \
    f32x2 pl = v0 * at0;                                                          \
    pl = v1 * at1 + pl;                                                           \
    pl = v2 * at2 + pl;                                                           \
    pl = v3 * at3 + pl;                                                           \
    float part = pl.x + pl.y;                                                     \
    DPPADD(part, 0x121, 0xf);  /* row_ror:1 */                                    \
    DPPADD(part, 0x122, 0xf);  /* row_ror:2 */                                    \
    DPPADD(part, 0x124, 0xf);  /* row_ror:4 */                                    \
    DPPADD(part, 0x128, 0xf);  /* row_ror:8 -> all 16 lanes hold node sum */      \
    float p = __builtin_amdgcn_exp2f(part);                                       \
    p = (i + (J) < rem) ? p : 0.f;                                                \
    s += p;                                                                       \
    a0 = p * xs0 + a0; a1 = p * xs1 + a1;                                         \
    a2 = p * xs2 + a2; a3 = p * xs3 + a3;                                         \
  }

  for (int i = 0; i < trips; i += 4) {
    x1 = *(const uint4*)&XLg[(e1.x & 0xffffu) * 64];
    BODY(e0, x0, 0);
    e0 = edat[beg + i + 4];
    x0 = *(const uint4*)&XLg[(e2.x & 0xffffu) * 64];
    BODY(e1, x1, 1);
    e1 = edat[beg + i + 5];
    x1 = *(const uint4*)&XLg[(e3.x & 0xffffu) * 64];
    BODY(e2, x0, 2);
    e2 = edat[beg + i + 6];
    x0 = *(const uint4*)&XLg[(e0.x & 0xffffu) * 64];
    BODY(e3, x1, 3);
    e3 = edat[beg + i + 7];
  }
#undef BODY

  float inv = 1.f / s;
  f32x2 b0 = *(const f32x2*)&bias[c0];
  f32x2 b1 = *(const f32x2*)&bias[c0 + 2];
  f32x2 b2 = *(const f32x2*)&bias[c0 + 4];
  f32x2 b3 = *(const f32x2*)&bias[c0 + 6];
  f32x2 o0 = a0 * inv + b0;
  f32x2 o1 = a1 * inv + b1;
  f32x2 o2 = a2 * inv + b2;
  f32x2 o3 = a3 * inv + b3;
  uint4 o;
  o.x = pack2(o0.x, o0.y);
  o.y = pack2(o1.x, o1.y);
  o.z = pack2(o2.x, o2.y);
  o.w = pack2(o3.x, o3.y);
  *(uint4*)&Hb[orig * 64 + l4 * 4] = o;
}

// ---------------- BN stats ----------------

__global__ __launch_bounds__(256) void k_bnstats(const unsigned* __restrict__ Hb,
                                                 float* __restrict__ cs) {
  __shared__ float red[8][256];
  int t = threadIdx.x;
  int ui = (t & 31) * 2;
  int c0 = ui * 2;
  int grp = t >> 5;
  int chunk = (NN + gridDim.x - 1) / gridDim.x;
  int n0 = blockIdx.x * chunk, n1 = min(n0 + chunk, NN);
  float s10 = 0.f, s11 = 0.f, s12 = 0.f, s13 = 0.f;
  float s20 = 0.f, s21 = 0.f, s22 = 0.f, s23 = 0.f;
  for (int n = n0 + grp; n < n1; n += 8) {
    uint2 h = *(const uint2*)&Hb[n * 64 + ui];
    float v0 = fmaxf(bf_lo(h.x), 0.f), v1 = fmaxf(bf_hi(h.x), 0.f);
    float v2 = fmaxf(bf_lo(h.y), 0.f), v3 = fmaxf(bf_hi(h.y), 0.f);
    s10 += v0; s11 += v1; s12 += v2; s13 += v3;
    s20 += v0 * v0; s21 += v1 * v1; s22 += v2 * v2; s23 += v3 * v3;
  }
  red[grp][c0 + 0] = s10; red[grp][c0 + 1] = s11;
  red[grp][c0 + 2] = s12; red[grp][c0 + 3] = s13;
  red[grp][128 + c0 + 0] = s20; red[grp][128 + c0 + 1] = s21;
  red[grp][128 + c0 + 2] = s22; red[grp][128 + c0 + 3] = s23;
  __syncthreads();
  float sum = 0.f;
#pragma unroll
  for (int g2 = 0; g2 < 8; ++g2) sum += red[g2][t];
  atomicAdd(&cs[t], sum);
}

// ---------------- pooling ----------------

__global__ __launch_bounds__(256) void k_pool(const unsigned* __restrict__ Hb,
    const int* __restrict__ batch, const float* __restrict__ cs,
    const float* __restrict__ g, const float* __restrict__ b,
    unsigned* __restrict__ pooled) {
  int t = threadIdx.x;
  int ui = (t & 31) * 2;
  int c0 = ui * 2;
  int grp = t >> 5;
  float scv0, scv1, scv2, scv3, shv0, shv1, shv2, shv3;
  {
    float mu, var;
    mu = cs[c0 + 0] * (1.f / NN); var = fmaxf(cs[HID + c0 + 0] * (1.f / NN) - mu * mu, 0.f);
    scv0 = g[c0 + 0] * rsqrtf(var + BNEPS); shv0 = b[c0 + 0] - mu * scv0;
    mu = cs[c0 + 1] * (1.f / NN); var = fmaxf(cs[HID + c0 + 1] * (1.f / NN) - mu * mu, 0.f);
    scv1 = g[c0 + 1] * rsqrtf(var + BNEPS); shv1 = b[c0 + 1] - mu * scv1;
    mu = cs[c0 + 2] * (1.f / NN); var = fmaxf(cs[HID + c0 + 2] * (1.f / NN) - mu * mu, 0.f);
    scv2 = g[c0 + 2] * rsqrtf(var + BNEPS); shv2 = b[c0 + 2] - mu * scv2;
    mu = cs[c0 + 3] * (1.f / NN); var = fmaxf(cs[HID + c0 + 3] * (1.f / NN) - mu * mu, 0.f);
    scv3 = g[c0 + 3] * rsqrtf(var + BNEPS); shv3 = b[c0 + 3] - mu * scv3;
  }
  int chunk = (NN + gridDim.x - 1) / gridDim.x;
  int n0 = blockIdx.x * chunk, n1 = min(n0 + chunk, NN);
  int curg = -1;
  float m0 = -3.402823e38f, m1 = m0, m2 = m0, m3 = m0;
  for (int n = n0 + grp; n < n1; n += 8) {
    int gg = batch[n];
    if (gg != curg) {
      if (curg >= 0) {
        atomicMax(&pooled[curg * HID + c0 + 0], fenc(m0));
        atomicMax(&pooled[curg * HID + c0 + 1], fenc(m1));
        atomicMax(&pooled[curg * HID + c0 + 2], fenc(m2));
        atomicMax(&pooled[curg * HID + c0 + 3], fenc(m3));
      }
      curg = gg;
      m0 = m1 = m2 = m3 = -3.402823e38f;
    }
    uint2 h = *(const uint2*)&Hb[n * 64 + ui];
    m0 = fmaxf(m0, fmaxf(bf_lo(h.x), 0.f) * scv0 + shv0);
    m1 = fmaxf(m1, fmaxf(bf_hi(h.x), 0.f) * scv1 + shv1);
    m2 = fmaxf(m2, fmaxf(bf_lo(h.y), 0.f) * scv2 + shv2);
    m3 = fmaxf(m3, fmaxf(bf_hi(h.y), 0.f) * scv3 + shv3);
  }
  if (curg >= 0) {
    atomicMax(&pooled[curg * HID + c0 + 0], fenc(m0));
    atomicMax(&pooled[curg * HID + c0 + 1], fenc(m1));
    atomicMax(&pooled[curg * HID + c0 + 2], fenc(m2));
    atomicMax(&pooled[curg * HID + c0 + 3], fenc(m3));
  }
}

// ---------------- FC head ----------------

__global__ __launch_bounds__(128) void k_fc(const unsigned* __restrict__ pooled,
    const float* __restrict__ W1, const float* __restrict__ b1,
    const float* __restrict__ W2, const float* __restrict__ b2,
    float* __restrict__ out) {
  __shared__ float P[HID];
  __shared__ float Z[HID];
  int g = blockIdx.x, c = threadIdx.x;
  unsigned k = pooled[g * HID + c];
  P[c] = (k & 0x80000000u) ? __uint_as_float(k ^ 0x80000000u) : __uint_as_float(~k);
  __syncthreads();
  float acc = b1[c];
  for (int kk = 0; kk < HID; ++kk) acc += P[kk] * W1[kk * HID + c];
  Z[c] = fmaxf(acc, 0.f);
  __syncthreads();
  if (c < 40) {
    float a2 = b2[c];
    for (int kk = 0; kk < HID; ++kk) a2 += Z[kk] * W2[kk * 40 + c];
    out[g * 40 + c] = a2;
  }
}

// ---------------- launch ----------------

extern "C" void kernel_launch(void* const* d_in, const int* in_sizes, int n_in,
                              void* d_out, int out_size, void* d_ws, size_t ws_size,
                              hipStream_t stream) {
  (void)in_sizes; (void)n_in; (void)out_size; (void)ws_size;
  const float* x     = (const float*)d_in[0];
  const float* eattr = (const float*)d_in[1];
  const int*   ei    = (const int*)d_in[2];
  const int*   batch = (const int*)d_in[3];
  const float* W0l   = (const float*)d_in[4];
  const float* W0r   = (const float*)d_in[5];
  const float* We0   = (const float*)d_in[6];
  const float* a0    = (const float*)d_in[7];
  const float* b0    = (const float*)d_in[8];
  const float* bn0g  = (const float*)d_in[9];
  const float* bn0b  = (const float*)d_in[10];
  const float* Wl    = (const float*)d_in[11];
  const float* Wel   = (const float*)d_in[12];
  const float* al    = (const float*)d_in[13];
  const float* bl    = (const float*)d_in[14];
  const float* bng   = (const float*)d_in[15];
  const float* bnb   = (const float*)d_in[16];
  const float* fc1W  = (const float*)d_in[17];
  const float* fc1b  = (const float*)d_in[18];
  const float* fc2W  = (const float*)d_in[19];
  const float* fc2b  = (const float*)d_in[20];
  float* out = (float*)d_out;

  char* ws = (char*)d_ws;
  unsigned* Hbf  = (unsigned*)(ws + 0);            // 12,800,000  (bf16 H)
  unsigned* Abf  = (unsigned*)(ws + 12800000);     // 12,800,000  (bf16 features)
  unsigned* X0bf = (unsigned*)(ws + 25600000);     // 12,800,000  (layer0 XR, bf16)
  uint2*    edat = (uint2*)(ws + 38400000);        // (850000+256)*8 = 6,802,048
  int*      rowp = (int*)(ws + 45202048);          // 50001*4
  int*      pos  = (int*)(ws + 45402112);          // 3,200,000
  unsigned* wtb   = (unsigned*)(ws + 48602112);    // 32,768
  float*    bias2 = (float*)(ws + 48634880);       // 512
  int*      ord  = (int*)(ws + 48635392);          // 200,000
  int*      rank = (int*)(ws + 48835392);          // 200,000
  int*      dbase = (int*)(ws + 49035392);         // 4,096
  char*     zb   = ws + 49039488;                  // zeroed region start
  int*      deg  = (int*)(zb + 0);                 // 200,000
  float*    cs   = (float*)(zb + 200000);          // 3,072
  unsigned* pooled = (unsigned*)(zb + 203072);     // 16,384
  int*      bsum = (int*)(zb + 219456);            // 256
  int*      dhist = (int*)(zb + 219712);           // 4,096
  int*      dfill = (int*)(zb + 223808);           // 4,096
  const size_t ZLEN = 227904;

  hipMemsetAsync(zb, 0, ZLEN, stream);

  // CSR build over degree-sorted node order (two-level histograms)
  k_hist<<<(NE + 255) / 256, 256, 0, stream>>>(ei, deg, pos);
  k_dhist<<<49, 1024, 0, stream>>>(deg, dhist);
  k_dscan<<<1, 1024, 0, stream>>>(dhist, dbase);
  k_dscatter<<<49, 1024, 0, stream>>>(deg, dbase, dfill, ord, rank);
  k_scanA<<<49, 1024, 0, stream>>>(deg, ord, rowp, bsum);
  k_scanB<<<1, 64, 0, stream>>>(bsum, rowp, edat);
  k_scanC<<<49, 1024, 0, stream>>>(rowp, bsum);
  k_scatter<<<(NE + 255) / 256, 256, 0, stream>>>(ei, eattr, rowp, pos, rank, edat);
  k_selfmean<<<(NN + 255) / 256, 256, 0, stream>>>(rowp, ord, edat);

  // layer 0
  k_xform0<<<(NN * 32) / 256, 256, 0, stream>>>(x, W0l, W0r, Abf, X0bf);
  k_edge<<<(NN + 15) / 16, 256, 0, stream>>>(Abf, X0bf, edat, rowp, ord, We0, a0, b0, Hbf);
  k_bnstats<<<512, 256, 0, stream>>>(Hbf, cs);

  // layer 1
  k_wprep<<<1, 256, 0, stream>>>(Wl, cs, bn0g, bn0b, wtb, bias2);
  k_gemm<<<391, 256, 0, stream>>>(Hbf, wtb, bias2, Abf);
  k_edge<<<(NN + 15) / 16, 256, 0, stream>>>(Abf, Abf, edat, rowp, ord, Wel, al, bl, Hbf);
  k_bnstats<<<512, 256, 0, stream>>>(Hbf, cs + 256);

  // layer 2
  k_wprep<<<1, 256, 0, stream>>>(Wl + 128 * 128, cs + 256, bng, bnb, wtb, bias2);
  k_gemm<<<391, 256, 0, stream>>>(Hbf, wtb, bias2, Abf);
  k_edge<<<(NN + 15) / 16, 256, 0, stream>>>(Abf, Abf, edat, rowp, ord, Wel + 384, al + 128, bl + 128, Hbf);
  k_bnstats<<<512, 256, 0, stream>>>(Hbf, cs + 512);

  // pool + FC head
  k_pool<<<512, 256, 0, stream>>>(Hbf, batch, cs + 512, bng + 128, bnb + 128, pooled);
  k_fc<<<NG, 128, 0, stream>>>(pooled, fc1W, fc1b, fc2W, fc2b, out);
}

// Round 16
// 344.170 us; speedup vs baseline: 2.8145x; 2.8145x over previous
//
#include <hip/hip_runtime.h>

#define NN 50000
#define NE 800000
#define NG 32
#define HID 128
#define BNEPS 1e-5f
#define NETOT (NE + NN)  // 850000, CSR total incl self loops

typedef float f32x2 __attribute__((ext_vector_type(2)));
typedef float f32x4 __attribute__((ext_vector_type(4)));
typedef short bf16x8 __attribute__((ext_vector_type(8)));

__device__ __forceinline__ unsigned fenc(float f) {
  unsigned u = __float_as_uint(f);
  return (u & 0x80000000u) ? ~u : (u | 0x80000000u);
}

__device__ __forceinline__ unsigned bfr(float f) {
  unsigned u = __float_as_uint(f);
  return (u + 0x7fffu + ((u >> 16) & 1u)) >> 16;
}
__device__ __forceinline__ unsigned pack2(float a, float b) {
  return bfr(a) | (bfr(b) << 16);
}
__device__ __forceinline__ float bf_lo(unsigned u) { return __uint_as_float(u << 16); }
__device__ __forceinline__ float bf_hi(unsigned u) { return __uint_as_float(u & 0xffff0000u); }

#define DPPADD(x, ctrl, rmask)                                                   \
  (x) += __int_as_float(__builtin_amdgcn_update_dpp(0, __float_as_int(x),        \
                                                    (ctrl), (rmask), 0xf, true))

// ---------------- preprocessing ----------------

__global__ __launch_bounds__(256) void k_hist(const int* __restrict__ ei,
                                              int* __restrict__ deg,
                                              int* __restrict__ pos) {
  int e = blockIdx.x * 256 + threadIdx.x;
  if (e >= NE) return;
  pos[e] = atomicAdd(&deg[ei[NE + e]], 1);
}

// ---- degree sort: two-level histogram (LDS first) to avoid atomic contention ----

__global__ __launch_bounds__(1024) void k_dhist(const int* __restrict__ deg,
                                                int* __restrict__ dhist) {
  __shared__ int lh[1024];
  int t = threadIdx.x;
  lh[t] = 0;
  __syncthreads();
  int n = blockIdx.x * 1024 + t;
  if (n < NN) atomicAdd(&lh[min(deg[n], 1023)], 1);
  __syncthreads();
  if (lh[t]) atomicAdd(&dhist[t], lh[t]);
}

__global__ __launch_bounds__(1024) void k_dscan(const int* __restrict__ dhist,
                                                int* __restrict__ dbase) {
  __shared__ int wsum[16];
  int t = threadIdx.x, lane = t & 63, w = t >> 6;
  int v = dhist[t];
  int s = v;
#pragma unroll
  for (int off = 1; off < 64; off <<= 1) {
    int y = __shfl_up(s, off, 64);
    if (lane >= off) s += y;
  }
  if (lane == 63) wsum[w] = s;
  __syncthreads();
  if (t < 16) {
    int xv = wsum[t];
#pragma unroll
    for (int off = 1; off < 16; off <<= 1) {
      int y = __shfl_up(xv, off, 64);
      if (t >= off) xv += y;
    }
    wsum[t] = xv;
  }
  __syncthreads();
  int incl = s + ((w == 0) ? 0 : wsum[w - 1]);
  dbase[t] = NN - incl;  // descending-degree base
}

__global__ __launch_bounds__(1024) void k_dscatter(const int* __restrict__ deg,
    const int* __restrict__ dbase, int* __restrict__ dfill,
    int* __restrict__ ord, int* __restrict__ rank) {
  __shared__ int lh[1024];
  __shared__ int lbase[1024];
  int t = threadIdx.x;
  lh[t] = 0;
  __syncthreads();
  int n = blockIdx.x * 1024 + t;
  int d = 0, lp = 0;
  if (n < NN) {
    d = min(deg[n], 1023);
    lp = atomicAdd(&lh[d], 1);  // local position within block's degree bucket
  }
  __syncthreads();
  if (lh[t]) lbase[t] = atomicAdd(&dfill[t], lh[t]);  // block base per degree
  __syncthreads();
  if (n < NN) {
    int p = dbase[d] + lbase[d] + lp;
    ord[p] = n;
    rank[n] = p;
  }
}

// hierarchical scan over SORTED degree order
__global__ __launch_bounds__(1024) void k_scanA(const int* __restrict__ deg,
                                                const int* __restrict__ ord,
                                                int* __restrict__ rowp,
                                                int* __restrict__ bsum) {
  __shared__ int wsum[16];
  int t = threadIdx.x, lane = t & 63, w = t >> 6;
  int i = blockIdx.x * 1024 + t;
  int v = (i < NN) ? (deg[ord[i]] + 1) : 0;  // +1 self loop
  int s = v;
#pragma unroll
  for (int off = 1; off < 64; off <<= 1) {
    int y = __shfl_up(s, off, 64);
    if (lane >= off) s += y;
  }
  if (lane == 63) wsum[w] = s;
  __syncthreads();
  if (t < 16) {
    int xv = wsum[t];
#pragma unroll
    for (int off = 1; off < 16; off <<= 1) {
      int y = __shfl_up(xv, off, 64);
      if (t >= off) xv += y;
    }
    wsum[t] = xv;
  }
  __syncthreads();
  int wexcl = (w == 0) ? 0 : wsum[w - 1];
  int incl = wexcl + s;
  if (i < NN) rowp[i] = incl - v;  // block-local exclusive
  if (t == 1023) bsum[blockIdx.x] = incl;
}

__global__ __launch_bounds__(64) void k_scanB(int* __restrict__ bsum,
                                              int* __restrict__ rowp,
                                              uint2* __restrict__ edat) {
  int t = threadIdx.x;  // one wave; 49 block sums
  int v = (t < 49) ? bsum[t] : 0;
  int s = v;
#pragma unroll
  for (int off = 1; off < 64; off <<= 1) {
    int y = __shfl_up(s, off, 64);
    if (t >= off) s += y;
  }
  bsum[t] = s - v;                 // exclusive
  if (t == 48) rowp[NN] = s;       // total (== NETOT)
  for (int j = t; j < 256; j += 64) {  // zero pad entries (clamp-free prefetch)
    uint2 z; z.x = 0u; z.y = 0u;
    edat[NETOT + j] = z;
  }
}

__global__ __launch_bounds__(1024) void k_scanC(int* __restrict__ rowp,
                                                const int* __restrict__ bsum) {
  int i = blockIdx.x * 1024 + threadIdx.x;
  if (i < NN) rowp[i] += bsum[blockIdx.x];
}

// scatter edges into SORTED dst-CSR order (atomic-free)
__global__ __launch_bounds__(256) void k_scatter(const int* __restrict__ ei,
    const float* __restrict__ eattr, const int* __restrict__ rowp,
    const int* __restrict__ pos, const int* __restrict__ rank,
    uint2* __restrict__ edat) {
  int e = blockIdx.x * 256 + threadIdx.x;
  if (e >= NE) return;
  int d = ei[NE + e];
  int p = rowp[rank[d]] + pos[e];
  uint2 v;
  v.x = (unsigned)ei[e] | (bfr(eattr[e * 3 + 0]) << 16);
  v.y = bfr(eattr[e * 3 + 1]) | (bfr(eattr[e * 3 + 2]) << 16);
  edat[p] = v;
}

// self-loop entry: mean of incoming edge attrs. one THREAD per sorted node.
__global__ __launch_bounds__(256) void k_selfmean(const int* __restrict__ rowp,
                                                  const int* __restrict__ ord,
                                                  uint2* __restrict__ edat) {
  int n = blockIdx.x * 256 + threadIdx.x;
  if (n >= NN) return;
  int beg = rowp[n], endm1 = rowp[n + 1] - 1;
  float s0 = 0.f, s1 = 0.f, s2 = 0.f;
  for (int i = beg; i < endm1; ++i) {
    uint2 v = edat[i];
    s0 += bf_hi(v.x); s1 += bf_lo(v.y); s2 += bf_hi(v.y);
  }
  int cnt = endm1 - beg;
  float inv = cnt > 0 ? 1.f / (float)cnt : 0.f;
  uint2 o;
  o.x = (unsigned)ord[n] | (bfr(s0 * inv) << 16);
  o.y = bfr(s1 * inv) | (bfr(s2 * inv) << 16);
  edat[endm1] = o;
}

// ---------------- layer 0 input transform ----------------

__global__ __launch_bounds__(256) void k_xform0(const float* __restrict__ x,
    const float* __restrict__ W0l, const float* __restrict__ W0r,
    unsigned* __restrict__ A, unsigned* __restrict__ B) {
  int t = blockIdx.x * 256 + threadIdx.x;
  int n = t >> 5;
  int c = (t & 31) * 4;
  if (n >= NN) return;
  float x0 = x[n * 3 + 0], x1 = x[n * 3 + 1], x2 = x[n * 3 + 2];
  float4 a0 = *(const float4*)&W0l[c];
  float4 a1 = *(const float4*)&W0l[HID + c];
  float4 a2 = *(const float4*)&W0l[2 * HID + c];
  float oax = x0 * a0.x + x1 * a1.x + x2 * a2.x;
  float oay = x0 * a0.y + x1 * a1.y + x2 * a2.y;
  float oaz = x0 * a0.z + x1 * a1.z + x2 * a2.z;
  float oaw = x0 * a0.w + x1 * a1.w + x2 * a2.w;
  uint2 pa;
  pa.x = pack2(oax, oay);
  pa.y = pack2(oaz, oaw);
  *(uint2*)&A[n * 64 + (c >> 1)] = pa;
  float4 b0 = *(const float4*)&W0r[c];
  float4 b1 = *(const float4*)&W0r[HID + c];
  float4 b2 = *(const float4*)&W0r[2 * HID + c];
  float obx = x0 * b0.x + x1 * b1.x + x2 * b2.x;
  float oby = x0 * b0.y + x1 * b1.y + x2 * b2.y;
  float obz = x0 * b0.z + x1 * b1.z + x2 * b2.z;
  float obw = x0 * b0.w + x1 * b1.w + x2 * b2.w;
  uint2 pb;
  pb.x = pack2(obx, oby);
  pb.y = pack2(obz, obw);
  *(uint2*)&B[n * 64 + (c >> 1)] = pb;
}

// ---------------- weight prep ----------------

__global__ __launch_bounds__(256) void k_wprep(const float* __restrict__ W,
    const float* __restrict__ cs, const float* __restrict__ g,
    const float* __restrict__ b, unsigned* __restrict__ Wt,
    float* __restrict__ bias2) {
  __shared__ float scS[HID], shS[HID];
  int t = threadIdx.x;
  if (t < HID) {
    float mu = cs[t] * (1.f / NN);
    float var = fmaxf(cs[HID + t] * (1.f / NN) - mu * mu, 0.f);
    float sc = g[t] * rsqrtf(var + BNEPS);
    scS[t] = sc;
    shS[t] = b[t] - mu * sc;
  }
  __syncthreads();
  for (int i = t; i < HID * 64; i += 256) {
    int n = i >> 6, kp = (i & 63) * 2;
    Wt[i] = pack2(scS[kp] * W[kp * HID + n], scS[kp + 1] * W[(kp + 1) * HID + n]);
  }
  if (t < HID) {
    float acc = 0.f;
    for (int k = 0; k < HID; ++k) acc += shS[k] * W[k * HID + t];
    bias2[t] = acc;
  }
}

// ---------------- GEMM (MFMA), 2 tiles per block ----------------

__global__ __launch_bounds__(256) void k_gemm(const unsigned* __restrict__ Hb,
    const unsigned* __restrict__ Wt, const float* __restrict__ bias2,
    unsigned* __restrict__ A) {
  __shared__ unsigned WsL[HID * 68];  // [128][68] pad, 34.8KB
  int t = threadIdx.x;
  for (int i4 = t * 4; i4 < HID * 64; i4 += 1024) {
    uint4 v = *(const uint4*)&Wt[i4];
    *(uint4*)&WsL[(i4 >> 6) * 68 + (i4 & 63)] = v;
  }
  __syncthreads();
  int l = t & 63;
  int w = t >> 6;
  int l15 = l & 15;
  int kg = (l >> 4) * 4;
  float bl[8];
#pragma unroll
  for (int nt = 0; nt < 8; ++nt) bl[nt] = bias2[nt * 16 + l15];
  for (int rb = blockIdx.x; rb * 64 < NN; rb += gridDim.x) {
    int r0 = rb * 64 + w * 16;
    int arow = min(r0 + l15, NN - 1);
    f32x4 acc[8] = {};
#pragma unroll
    for (int ks = 0; ks < 4; ++ks) {
      uint4 au = *(const uint4*)&Hb[arow * 64 + ks * 16 + kg];
      au.x &= ~(((au.x >> 15) & 0x10001u) * 0xFFFFu);  // packed relu
      au.y &= ~(((au.y >> 15) & 0x10001u) * 0xFFFFu);
      au.z &= ~(((au.z >> 15) & 0x10001u) * 0xFFFFu);
      au.w &= ~(((au.w >> 15) & 0x10001u) * 0xFFFFu);
      bf16x8 af = *(bf16x8*)&au;
#pragma unroll
      for (int nt = 0; nt < 8; ++nt) {
        uint4 bu = *(const uint4*)&WsL[(nt * 16 + l15) * 68 + ks * 16 + kg];
        bf16x8 bf = *(bf16x8*)&bu;
        acc[nt] = __builtin_amdgcn_mfma_f32_16x16x32_bf16(af, bf, acc[nt], 0, 0, 0);
      }
    }
#pragma unroll
    for (int nt = 0; nt < 8; ++nt) {
#pragma unroll
      for (int reg = 0; reg < 4; ++reg) {
        float v = acc[nt][reg] + bl[nt];
        float nb = __shfl_down(v, 1, 64);
        int rm = r0 + (l >> 4) * 4 + reg;
        if (((l & 1) == 0) && rm < NN)
          A[rm * 64 + nt * 8 + (l15 >> 1)] = pack2(v, nb);
      }
    }
  }
}

// ---- GATv2 edge phase v12: sorted nodes, 4 dst/wave, 2 live gather buffers,
//      natural register allocation (no occupancy pin) ----

__global__ __launch_bounds__(256) void k_edge(const unsigned* __restrict__ XL,
    const unsigned* __restrict__ XR, const uint2* __restrict__ edat,
    const int* __restrict__ rowp, const int* __restrict__ ord,
    const float* __restrict__ We, const float* __restrict__ att,
    const float* __restrict__ bias, unsigned* __restrict__ Hb) {
  __shared__ float WeS[3 * HID];
  int t = threadIdx.x;
  for (int i = t; i < 3 * HID; i += 256) WeS[i] = We[i];
  __syncthreads();
  int lane = t & 63;
  int l4 = lane & 15;
  int n = blockIdx.x * 16 + (t >> 6) * 4 + (lane >> 4);  // sorted slot
  int orig = ord[n];
  int c0 = l4 * 8;
  uint4 urx = *(const uint4*)&XR[orig * 64 + l4 * 4];
  f32x2 xr0 = {bf_lo(urx.x), bf_hi(urx.x)};
  f32x2 xr1 = {bf_lo(urx.y), bf_hi(urx.y)};
  f32x2 xr2 = {bf_lo(urx.z), bf_hi(urx.z)};
  f32x2 xr3 = {bf_lo(urx.w), bf_hi(urx.w)};
  f32x2 at0 = *(const f32x2*)&att[c0];
  f32x2 at1 = *(const f32x2*)&att[c0 + 2];
  f32x2 at2 = *(const f32x2*)&att[c0 + 4];
  f32x2 at3 = *(const f32x2*)&att[c0 + 6];
  at0 *= 1.44269504f; at1 *= 1.44269504f; at2 *= 1.44269504f; at3 *= 1.44269504f;
  f32x2 w00 = *(const f32x2*)&WeS[c0],         w01 = *(const f32x2*)&WeS[c0 + 2];
  f32x2 w02 = *(const f32x2*)&WeS[c0 + 4],     w03 = *(const f32x2*)&WeS[c0 + 6];
  f32x2 w10 = *(const f32x2*)&WeS[HID + c0],   w11 = *(const f32x2*)&WeS[HID + c0 + 2];
  f32x2 w12 = *(const f32x2*)&WeS[HID + c0+4], w13 = *(const f32x2*)&WeS[HID + c0 + 6];
  f32x2 w20 = *(const f32x2*)&WeS[2*HID + c0],   w21 = *(const f32x2*)&WeS[2*HID + c0 + 2];
  f32x2 w22 = *(const f32x2*)&WeS[2*HID + c0+4], w23 = *(const f32x2*)&WeS[2*HID + c0 + 6];
  int beg = rowp[n], end = rowp[n + 1];
  int rem = end - beg;
  int tc = rem;
  tc = max(tc, __shfl_xor(tc, 16, 64));
  tc = max(tc, __shfl_xor(tc, 32, 64));
  int trips = (__builtin_amdgcn_readfirstlane(tc) + 3) & ~3;
  const unsigned* XLg = XL + l4 * 4;

  uint2 e0 = edat[beg], e1 = edat[beg + 1], e2 = edat[beg + 2], e3 = edat[beg + 3];
  uint4 x0 = *(const uint4*)&XLg[(e0.x & 0xffffu) * 64];
  uint4 x1;
  f32x2 a0 = {0.f, 0.f}, a1 = {0.f, 0.f}, a2 = {0.f, 0.f}, a3 = {0.f, 0.f};
  float s = 0.f;

#define BODY(ED, XU, J)                                                           \
  {                                                                               \
    f32x2 xs0 = {bf_lo(XU.x), bf_hi(XU.x)};                                       \
    f32x2 xs1 = {bf_lo(XU.y), bf_hi(XU.y)};                                       \
    f32x2 xs2 = {bf_lo(XU.z), bf_hi(XU.z)};                                       \
    f32x2 xs3 = {bf_lo(XU.w), bf_hi(XU.w)};                                       \
    float ea0 = bf_hi(ED.x), ea1 = bf_lo(ED.y), ea2 = bf_hi(ED.y);                \
    f32x2 u0 = xs0 + xr0, u1 = xs1 + xr1, u2 = xs2 + xr2, u3 = xs3 + xr3;         \
    u0 = ea0 * w00 + u0; u1 = ea0 * w01 + u1; u2 = ea0 * w02 + u2; u3 = ea0 * w03 + u3; \
    u0 = ea1 * w10 + u0; u1 = ea1 * w11 + u1; u2 = ea1 * w12 + u2; u3 = ea1 * w13 + u3; \
    u0 = ea2 * w20 + u0; u1 = ea2 * w21 + u1; u2 = ea2 * w22 + u2; u3 = ea2 * w23 + u3; \
    f32x2 v0 = __builtin_elementwise_max(u0, 0.2f * u0);                          \
    f32x2 v1 = __builtin_elementwise_max(u1, 0.2f * u1);                          \
    f32x2 v2 = __builtin_elementwise_max(u2, 0.2f * u2);                          \
    f32x2 v3 = __builtin_elementwise_max(u3, 0.2f * u3);                          \
    f32x2 pl = v0 * at0;                                                          \
    pl = v1 * at1 + pl;                                                           \
    pl = v2 * at2 + pl;                                                           \
    pl = v3 * at3 + pl;                                                           \
    float part = pl.x + pl.y;                                                     \
    DPPADD(part, 0x121, 0xf);  /* row_ror:1 */                                    \
    DPPADD(part, 0x122, 0xf);  /* row_ror:2 */                                    \
    DPPADD(part, 0x124, 0xf);  /* row_ror:4 */                                    \
    DPPADD(part, 0x128, 0xf);  /* row_ror:8 -> all 16 lanes hold node sum */      \
    float p = __builtin_amdgcn_exp2f(part);                                       \
    p = (i + (J) < rem) ? p : 0.f;                                                \
    s += p;                                                                       \
    a0 = p * xs0 + a0; a1 = p * xs1 + a1;                                         \
    a2 = p * xs2 + a2; a3 = p * xs3 + a3;                                         \
  }

  for (int i = 0; i < trips; i += 4) {
    x1 = *(const uint4*)&XLg[(e1.x & 0xffffu) * 64];
    BODY(e0, x0, 0);
    e0 = edat[beg + i + 4];
    x0 = *(const uint4*)&XLg[(e2.x & 0xffffu) * 64];
    BODY(e1, x1, 1);
    e1 = edat[beg + i + 5];
    x1 = *(const uint4*)&XLg[(e3.x & 0xffffu) * 64];
    BODY(e2, x0, 2);
    e2 = edat[beg + i + 6];
    x0 = *(const uint4*)&XLg[(e0.x & 0xffffu) * 64];
    BODY(e3, x1, 3);
    e3 = edat[beg + i + 7];
  }
#undef BODY

  float inv = 1.f / s;
  f32x2 b0 = *(const f32x2*)&bias[c0];
  f32x2 b1 = *(const f32x2*)&bias[c0 + 2];
  f32x2 b2 = *(const f32x2*)&bias[c0 + 4];
  f32x2 b3 = *(const f32x2*)&bias[c0 + 6];
  f32x2 o0 = a0 * inv + b0;
  f32x2 o1 = a1 * inv + b1;
  f32x2 o2 = a2 * inv + b2;
  f32x2 o3 = a3 * inv + b3;
  uint4 o;
  o.x = pack2(o0.x, o0.y);
  o.y = pack2(o1.x, o1.y);
  o.z = pack2(o2.x, o2.y);
  o.w = pack2(o3.x, o3.y);
  *(uint4*)&Hb[orig * 64 + l4 * 4] = o;
}

// ---------------- BN stats ----------------

__global__ __launch_bounds__(256) void k_bnstats(const unsigned* __restrict__ Hb,
                                                 float* __restrict__ cs) {
  __shared__ float red[8][256];
  int t = threadIdx.x;
  int ui = (t & 31) * 2;
  int c0 = ui * 2;
  int grp = t >> 5;
  int chunk = (NN + gridDim.x - 1) / gridDim.x;
  int n0 = blockIdx.x * chunk, n1 = min(n0 + chunk, NN);
  float s10 = 0.f, s11 = 0.f, s12 = 0.f, s13 = 0.f;
  float s20 = 0.f, s21 = 0.f, s22 = 0.f, s23 = 0.f;
  for (int n = n0 + grp; n < n1; n += 8) {
    uint2 h = *(const uint2*)&Hb[n * 64 + ui];
    float v0 = fmaxf(bf_lo(h.x), 0.f), v1 = fmaxf(bf_hi(h.x), 0.f);
    float v2 = fmaxf(bf_lo(h.y), 0.f), v3 = fmaxf(bf_hi(h.y), 0.f);
    s10 += v0; s11 += v1; s12 += v2; s13 += v3;
    s20 += v0 * v0; s21 += v1 * v1; s22 += v2 * v2; s23 += v3 * v3;
  }
  red[grp][c0 + 0] = s10; red[grp][c0 + 1] = s11;
  red[grp][c0 + 2] = s12; red[grp][c0 + 3] = s13;
  red[grp][128 + c0 + 0] = s20; red[grp][128 + c0 + 1] = s21;
  red[grp][128 + c0 + 2] = s22; red[grp][128 + c0 + 3] = s23;
  __syncthreads();
  float sum = 0.f;
#pragma unroll
  for (int g2 = 0; g2 < 8; ++g2) sum += red[g2][t];
  atomicAdd(&cs[t], sum);
}

// ---------------- pooling ----------------

__global__ __launch_bounds__(256) void k_pool(const unsigned* __restrict__ Hb,
    const int* __restrict__ batch, const float* __restrict__ cs,
    const float* __restrict__ g, const float* __restrict__ b,
    unsigned* __restrict__ pooled) {
  int t = threadIdx.x;
  int ui = (t & 31) * 2;
  int c0 = ui * 2;
  int grp = t >> 5;
  float scv0, scv1, scv2, scv3, shv0, shv1, shv2, shv3;
  {
    float mu, var;
    mu = cs[c0 + 0] * (1.f / NN); var = fmaxf(cs[HID + c0 + 0] * (1.f / NN) - mu * mu, 0.f);
    scv0 = g[c0 + 0] * rsqrtf(var + BNEPS); shv0 = b[c0 + 0] - mu * scv0;
    mu = cs[c0 + 1] * (1.f / NN); var = fmaxf(cs[HID + c0 + 1] * (1.f / NN) - mu * mu, 0.f);
    scv1 = g[c0 + 1] * rsqrtf(var + BNEPS); shv1 = b[c0 + 1] - mu * scv1;
    mu = cs[c0 + 2] * (1.f / NN); var = fmaxf(cs[HID + c0 + 2] * (1.f / NN) - mu * mu, 0.f);
    scv2 = g[c0 + 2] * rsqrtf(var + BNEPS); shv2 = b[c0 + 2] - mu * scv2;
    mu = cs[c0 + 3] * (1.f / NN); var = fmaxf(cs[HID + c0 + 3] * (1.f / NN) - mu * mu, 0.f);
    scv3 = g[c0 + 3] * rsqrtf(var + BNEPS); shv3 = b[c0 + 3] - mu * scv3;
  }
  int chunk = (NN + gridDim.x - 1) / gridDim.x;
  int n0 = blockIdx.x * chunk, n1 = min(n0 + chunk, NN);
  int curg = -1;
  float m0 = -3.402823e38f, m1 = m0, m2 = m0, m3 = m0;
  for (int n = n0 + grp; n < n1; n += 8) {
    int gg = batch[n];
    if (gg != curg) {
      if (curg >= 0) {
        atomicMax(&pooled[curg * HID + c0 + 0], fenc(m0));
        atomicMax(&pooled[curg * HID + c0 + 1], fenc(m1));
        atomicMax(&pooled[curg * HID + c0 + 2], fenc(m2));
        atomicMax(&pooled[curg * HID + c0 + 3], fenc(m3));
      }
      curg = gg;
      m0 = m1 = m2 = m3 = -3.402823e38f;
    }
    uint2 h = *(const uint2*)&Hb[n * 64 + ui];
    m0 = fmaxf(m0, fmaxf(bf_lo(h.x), 0.f) * scv0 + shv0);
    m1 = fmaxf(m1, fmaxf(bf_hi(h.x), 0.f) * scv1 + shv1);
    m2 = fmaxf(m2, fmaxf(bf_lo(h.y), 0.f) * scv2 + shv2);
    m3 = fmaxf(m3, fmaxf(bf_hi(h.y), 0.f) * scv3 + shv3);
  }
  if (curg >= 0) {
    atomicMax(&pooled[curg * HID + c0 + 0], fenc(m0));
    atomicMax(&pooled[curg * HID + c0 + 1], fenc(m1));
    atomicMax(&pooled[curg * HID + c0 + 2], fenc(m2));
    atomicMax(&pooled[curg * HID + c0 + 3], fenc(m3));
  }
}

// ---------------- FC head ----------------

__global__ __launch_bounds__(128) void k_fc(const unsigned* __restrict__ pooled,
    const float* __restrict__ W1, const float* __restrict__ b1,
    const float* __restrict__ W2, const float* __restrict__ b2,
    float* __restrict__ out) {
  __shared__ float P[HID];
  __shared__ float Z[HID];
  int g = blockIdx.x, c = threadIdx.x;
  unsigned k = pooled[g * HID + c];
  P[c] = (k & 0x80000000u) ? __uint_as_float(k ^ 0x80000000u) : __uint_as_float(~k);
  __syncthreads();
  float acc = b1[c];
  for (int kk = 0; kk < HID; ++kk) acc += P[kk] * W1[kk * HID + c];
  Z[c] = fmaxf(acc, 0.f);
  __syncthreads();
  if (c < 40) {
    float a2 = b2[c];
    for (int kk = 0; kk < HID; ++kk) a2 += Z[kk] * W2[kk * 40 + c];
    out[g * 40 + c] = a2;
  }
}

// ---------------- launch ----------------

extern "C" void kernel_launch(void* const* d_in, const int* in_sizes, int n_in,
                              void* d_out, int out_size, void* d_ws, size_t ws_size,
                              hipStream_t stream) {
  (void)in_sizes; (void)n_in; (void)out_size; (void)ws_size;
  const float* x     = (const float*)d_in[0];
  const float* eattr = (const float*)d_in[1];
  const int*   ei    = (const int*)d_in[2];
  const int*   batch = (const int*)d_in[3];
  const float* W0l   = (const float*)d_in[4];
  const float* W0r   = (const float*)d_in[5];
  const float* We0   = (const float*)d_in[6];
  const float* a0    = (const float*)d_in[7];
  const float* b0    = (const float*)d_in[8];
  const float* bn0g  = (const float*)d_in[9];
  const float* bn0b  = (const float*)d_in[10];
  const float* Wl    = (const float*)d_in[11];
  const float* Wel   = (const float*)d_in[12];
  const float* al    = (const float*)d_in[13];
  const float* bl    = (const float*)d_in[14];
  const float* bng   = (const float*)d_in[15];
  const float* bnb   = (const float*)d_in[16];
  const float* fc1W  = (const float*)d_in[17];
  const float* fc1b  = (const float*)d_in[18];
  const float* fc2W  = (const float*)d_in[19];
  const float* fc2b  = (const float*)d_in[20];
  float* out = (float*)d_out;

  char* ws = (char*)d_ws;
  unsigned* Hbf  = (unsigned*)(ws + 0);            // 12,800,000  (bf16 H)
  unsigned* Abf  = (unsigned*)(ws + 12800000);     // 12,800,000  (bf16 features)
  unsigned* X0bf = (unsigned*)(ws + 25600000);     // 12,800,000  (layer0 XR, bf16)
  uint2*    edat = (uint2*)(ws + 38400000);        // (850000+256)*8 = 6,802,048
  int*      rowp = (int*)(ws + 45202048);          // 50001*4
  int*      pos  = (int*)(ws + 45402112);          // 3,200,000
  unsigned* wtb   = (unsigned*)(ws + 48602112);    // 32,768
  float*    bias2 = (float*)(ws + 48634880);       // 512
  int*      ord  = (int*)(ws + 48635392);          // 200,000
  int*      rank = (int*)(ws + 48835392);          // 200,000
  int*      dbase = (int*)(ws + 49035392);         // 4,096
  char*     zb   = ws + 49039488;                  // zeroed region start
  int*      deg  = (int*)(zb + 0);                 // 200,000
  float*    cs   = (float*)(zb + 200000);          // 3,072
  unsigned* pooled = (unsigned*)(zb + 203072);     // 16,384
  int*      bsum = (int*)(zb + 219456);            // 256
  int*      dhist = (int*)(zb + 219712);           // 4,096
  int*      dfill = (int*)(zb + 223808);           // 4,096
  const size_t ZLEN = 227904;

  hipMemsetAsync(zb, 0, ZLEN, stream);

  // CSR build over degree-sorted node order (two-level histograms)
  k_hist<<<(NE + 255) / 256, 256, 0, stream>>>(ei, deg, pos);
  k_dhist<<<49, 1024, 0, stream>>>(deg, dhist);
  k_dscan<<<1, 1024, 0, stream>>>(dhist, dbase);
  k_dscatter<<<49, 1024, 0, stream>>>(deg, dbase, dfill, ord, rank);
  k_scanA<<<49, 1024, 0, stream>>>(deg, ord, rowp, bsum);
  k_scanB<<<1, 64, 0, stream>>>(bsum, rowp, edat);
  k_scanC<<<49, 1024, 0, stream>>>(rowp, bsum);
  k_scatter<<<(NE + 255) / 256, 256, 0, stream>>>(ei, eattr, rowp, pos, rank, edat);
  k_selfmean<<<(NN + 255) / 256, 256, 0, stream>>>(rowp, ord, edat);

  // layer 0
  k_xform0<<<(NN * 32) / 256, 256, 0, stream>>>(x, W0l, W0r, Abf, X0bf);
  k_edge<<<(NN + 15) / 16, 256, 0, stream>>>(Abf, X0bf, edat, rowp, ord, We0, a0, b0, Hbf);
  k_bnstats<<<512, 256, 0, stream>>>(Hbf, cs);

  // layer 1
  k_wprep<<<1, 256, 0, stream>>>(Wl, cs, bn0g, bn0b, wtb, bias2);
  k_gemm<<<391, 256, 0, stream>>>(Hbf, wtb, bias2, Abf);
  k_edge<<<(NN + 15) / 16, 256, 0, stream>>>(Abf, Abf, edat, rowp, ord, Wel, al, bl, Hbf);
  k_bnstats<<<512, 256, 0, stream>>>(Hbf, cs + 256);

  // layer 2
  k_wprep<<<1, 256, 0, stream>>>(Wl + 128 * 128, cs + 256, bng, bnb, wtb, bias2);
  k_gemm<<<391, 256, 0, stream>>>(Hbf, wtb, bias2, Abf);
  k_edge<<<(NN + 15) / 16, 256, 0, stream>>>(Abf, Abf, edat, rowp, ord, Wel + 384, al + 128, bl + 128, Hbf);
  k_bnstats<<<512, 256, 0, stream>>>(Hbf, cs + 512);

  // pool + FC head
  k_pool<<<512, 256, 0, stream>>>(Hbf, batch, cs + 512, bng + 128, bnb + 128, pooled);
  k_fc<<<NG, 128, 0, stream>>>(pooled, fc1W, fc1b, fc2W, fc2b, out);
}

// Round 17
// 336.234 us; speedup vs baseline: 2.8809x; 1.0236x over previous
//
#include <hip/hip_runtime.h>

#define NN 50000
#define NE 800000
#define NG 32
#define HID 128
#define BNEPS 1e-5f
#define NETOT (NE + NN)  // 850000, CSR total incl self loops

typedef float f32x2 __attribute__((ext_vector_type(2)));
typedef float f32x4 __attribute__((ext_vector_type(4)));
typedef short bf16x8 __attribute__((ext_vector_type(8)));

__device__ __forceinline__ unsigned fenc(float f) {
  unsigned u = __float_as_uint(f);
  return (u & 0x80000000u) ? ~u : (u | 0x80000000u);
}

__device__ __forceinline__ unsigned bfr(float f) {
  unsigned u = __float_as_uint(f);
  return (u + 0x7fffu + ((u >> 16) & 1u)) >> 16;
}
__device__ __forceinline__ unsigned pack2(float a, float b) {
  return bfr(a) | (bfr(b) << 16);
}
__device__ __forceinline__ float bf_lo(unsigned u) { return __uint_as_float(u << 16); }
__device__ __forceinline__ float bf_hi(unsigned u) { return __uint_as_float(u & 0xffff0000u); }

#define DPPADD(x, ctrl, rmask)                                                   \
  (x) += __int_as_float(__builtin_amdgcn_update_dpp(0, __float_as_int(x),        \
                                                    (ctrl), (rmask), 0xf, true))

// ---------------- preprocessing ----------------

__global__ __launch_bounds__(256) void k_hist(const int* __restrict__ ei,
                                              int* __restrict__ deg,
                                              int* __restrict__ pos) {
  int e = blockIdx.x * 256 + threadIdx.x;
  if (e >= NE) return;
  pos[e] = atomicAdd(&deg[ei[NE + e]], 1);
}

// ---- degree sort: two-level histogram (LDS first) to avoid atomic contention ----

__global__ __launch_bounds__(1024) void k_dhist(const int* __restrict__ deg,
                                                int* __restrict__ dhist) {
  __shared__ int lh[1024];
  int t = threadIdx.x;
  lh[t] = 0;
  __syncthreads();
  int n = blockIdx.x * 1024 + t;
  if (n < NN) atomicAdd(&lh[min(deg[n], 1023)], 1);
  __syncthreads();
  if (lh[t]) atomicAdd(&dhist[t], lh[t]);
}

__global__ __launch_bounds__(1024) void k_dscan(const int* __restrict__ dhist,
                                                int* __restrict__ dbase) {
  __shared__ int wsum[16];
  int t = threadIdx.x, lane = t & 63, w = t >> 6;
  int v = dhist[t];
  int s = v;
#pragma unroll
  for (int off = 1; off < 64; off <<= 1) {
    int y = __shfl_up(s, off, 64);
    if (lane >= off) s += y;
  }
  if (lane == 63) wsum[w] = s;
  __syncthreads();
  if (t < 16) {
    int xv = wsum[t];
#pragma unroll
    for (int off = 1; off < 16; off <<= 1) {
      int y = __shfl_up(xv, off, 64);
      if (t >= off) xv += y;
    }
    wsum[t] = xv;
  }
  __syncthreads();
  int incl = s + ((w == 0) ? 0 : wsum[w - 1]);
  dbase[t] = NN - incl;  // descending-degree base
}

__global__ __launch_bounds__(1024) void k_dscatter(const int* __restrict__ deg,
    const int* __restrict__ dbase, int* __restrict__ dfill,
    int* __restrict__ ord, int* __restrict__ rank) {
  __shared__ int lh[1024];
  __shared__ int lbase[1024];
  int t = threadIdx.x;
  lh[t] = 0;
  __syncthreads();
  int n = blockIdx.x * 1024 + t;
  int d = 0, lp = 0;
  if (n < NN) {
    d = min(deg[n], 1023);
    lp = atomicAdd(&lh[d], 1);  // local position within block's degree bucket
  }
  __syncthreads();
  if (lh[t]) lbase[t] = atomicAdd(&dfill[t], lh[t]);  // block base per degree
  __syncthreads();
  if (n < NN) {
    int p = dbase[d] + lbase[d] + lp;
    ord[p] = n;
    rank[n] = p;
  }
}

// hierarchical scan over SORTED degree order
__global__ __launch_bounds__(1024) void k_scanA(const int* __restrict__ deg,
                                                const int* __restrict__ ord,
                                                int* __restrict__ rowp,
                                                int* __restrict__ bsum) {
  __shared__ int wsum[16];
  int t = threadIdx.x, lane = t & 63, w = t >> 6;
  int i = blockIdx.x * 1024 + t;
  int v = (i < NN) ? (deg[ord[i]] + 1) : 0;  // +1 self loop
  int s = v;
#pragma unroll
  for (int off = 1; off < 64; off <<= 1) {
    int y = __shfl_up(s, off, 64);
    if (lane >= off) s += y;
  }
  if (lane == 63) wsum[w] = s;
  __syncthreads();
  if (t < 16) {
    int xv = wsum[t];
#pragma unroll
    for (int off = 1; off < 16; off <<= 1) {
      int y = __shfl_up(xv, off, 64);
      if (t >= off) xv += y;
    }
    wsum[t] = xv;
  }
  __syncthreads();
  int wexcl = (w == 0) ? 0 : wsum[w - 1];
  int incl = wexcl + s;
  if (i < NN) rowp[i] = incl - v;  // block-local exclusive
  if (t == 1023) bsum[blockIdx.x] = incl;
}

__global__ __launch_bounds__(64) void k_scanB(int* __restrict__ bsum,
                                              int* __restrict__ rowp,
                                              uint2* __restrict__ edat) {
  int t = threadIdx.x;  // one wave; 49 block sums
  int v = (t < 49) ? bsum[t] : 0;
  int s = v;
#pragma unroll
  for (int off = 1; off < 64; off <<= 1) {
    int y = __shfl_up(s, off, 64);
    if (t >= off) s += y;
  }
  bsum[t] = s - v;                 // exclusive
  if (t == 48) rowp[NN] = s;       // total (== NETOT)
  for (int j = t; j < 256; j += 64) {  // zero pad entries (clamp-free prefetch)
    uint2 z; z.x = 0u; z.y = 0u;
    edat[NETOT + j] = z;
  }
}

__global__ __launch_bounds__(1024) void k_scanC(int* __restrict__ rowp,
                                                const int* __restrict__ bsum) {
  int i = blockIdx.x * 1024 + threadIdx.x;
  if (i < NN) rowp[i] += bsum[blockIdx.x];
}

// scatter edges into SORTED dst-CSR order (atomic-free)
__global__ __launch_bounds__(256) void k_scatter(const int* __restrict__ ei,
    const float* __restrict__ eattr, const int* __restrict__ rowp,
    const int* __restrict__ pos, const int* __restrict__ rank,
    uint2* __restrict__ edat) {
  int e = blockIdx.x * 256 + threadIdx.x;
  if (e >= NE) return;
  int d = ei[NE + e];
  int p = rowp[rank[d]] + pos[e];
  uint2 v;
  v.x = (unsigned)ei[e] | (bfr(eattr[e * 3 + 0]) << 16);
  v.y = bfr(eattr[e * 3 + 1]) | (bfr(eattr[e * 3 + 2]) << 16);
  edat[p] = v;
}

// self-loop entry: mean of incoming edge attrs. one THREAD per sorted node.
__global__ __launch_bounds__(256) void k_selfmean(const int* __restrict__ rowp,
                                                  const int* __restrict__ ord,
                                                  uint2* __restrict__ edat) {
  int n = blockIdx.x * 256 + threadIdx.x;
  if (n >= NN) return;
  int beg = rowp[n], endm1 = rowp[n + 1] - 1;
  float s0 = 0.f, s1 = 0.f, s2 = 0.f;
  for (int i = beg; i < endm1; ++i) {
    uint2 v = edat[i];
    s0 += bf_hi(v.x); s1 += bf_lo(v.y); s2 += bf_hi(v.y);
  }
  int cnt = endm1 - beg;
  float inv = cnt > 0 ? 1.f / (float)cnt : 0.f;
  uint2 o;
  o.x = (unsigned)ord[n] | (bfr(s0 * inv) << 16);
  o.y = bfr(s1 * inv) | (bfr(s2 * inv) << 16);
  edat[endm1] = o;
}

// ---------------- layer 0 input transform ----------------

__global__ __launch_bounds__(256) void k_xform0(const float* __restrict__ x,
    const float* __restrict__ W0l, const float* __restrict__ W0r,
    unsigned* __restrict__ A, unsigned* __restrict__ B) {
  int t = blockIdx.x * 256 + threadIdx.x;
  int n = t >> 5;
  int c = (t & 31) * 4;
  if (n >= NN) return;
  float x0 = x[n * 3 + 0], x1 = x[n * 3 + 1], x2 = x[n * 3 + 2];
  float4 a0 = *(const float4*)&W0l[c];
  float4 a1 = *(const float4*)&W0l[HID + c];
  float4 a2 = *(const float4*)&W0l[2 * HID + c];
  float oax = x0 * a0.x + x1 * a1.x + x2 * a2.x;
  float oay = x0 * a0.y + x1 * a1.y + x2 * a2.y;
  float oaz = x0 * a0.z + x1 * a1.z + x2 * a2.z;
  float oaw = x0 * a0.w + x1 * a1.w + x2 * a2.w;
  uint2 pa;
  pa.x = pack2(oax, oay);
  pa.y = pack2(oaz, oaw);
  *(uint2*)&A[n * 64 + (c >> 1)] = pa;
  float4 b0 = *(const float4*)&W0r[c];
  float4 b1 = *(const float4*)&W0r[HID + c];
  float4 b2 = *(const float4*)&W0r[2 * HID + c];
  float obx = x0 * b0.x + x1 * b1.x + x2 * b2.x;
  float oby = x0 * b0.y + x1 * b1.y + x2 * b2.y;
  float obz = x0 * b0.z + x1 * b1.z + x2 * b2.z;
  float obw = x0 * b0.w + x1 * b1.w + x2 * b2.w;
  uint2 pb;
  pb.x = pack2(obx, oby);
  pb.y = pack2(obz, obw);
  *(uint2*)&B[n * 64 + (c >> 1)] = pb;
}

// ---------------- weight prep ----------------

__global__ __launch_bounds__(256) void k_wprep(const float* __restrict__ W,
    const float* __restrict__ cs, const float* __restrict__ g,
    const float* __restrict__ b, unsigned* __restrict__ Wt,
    float* __restrict__ bias2) {
  __shared__ float scS[HID], shS[HID];
  int t = threadIdx.x;
  if (t < HID) {
    float mu = cs[t] * (1.f / NN);
    float var = fmaxf(cs[HID + t] * (1.f / NN) - mu * mu, 0.f);
    float sc = g[t] * rsqrtf(var + BNEPS);
    scS[t] = sc;
    shS[t] = b[t] - mu * sc;
  }
  __syncthreads();
  for (int i = t; i < HID * 64; i += 256) {
    int n = i >> 6, kp = (i & 63) * 2;
    Wt[i] = pack2(scS[kp] * W[kp * HID + n], scS[kp + 1] * W[(kp + 1) * HID + n]);
  }
  if (t < HID) {
    float acc = 0.f;
    for (int k = 0; k < HID; ++k) acc += shS[k] * W[k * HID + t];
    bias2[t] = acc;
  }
}

// ---------------- GEMM (MFMA), 2 tiles per block ----------------

__global__ __launch_bounds__(256) void k_gemm(const unsigned* __restrict__ Hb,
    const unsigned* __restrict__ Wt, const float* __restrict__ bias2,
    unsigned* __restrict__ A) {
  __shared__ unsigned WsL[HID * 68];  // [128][68] pad, 34.8KB
  int t = threadIdx.x;
  for (int i4 = t * 4; i4 < HID * 64; i4 += 1024) {
    uint4 v = *(const uint4*)&Wt[i4];
    *(uint4*)&WsL[(i4 >> 6) * 68 + (i4 & 63)] = v;
  }
  __syncthreads();
  int l = t & 63;
  int w = t >> 6;
  int l15 = l & 15;
  int kg = (l >> 4) * 4;
  float bl[8];
#pragma unroll
  for (int nt = 0; nt < 8; ++nt) bl[nt] = bias2[nt * 16 + l15];
  for (int rb = blockIdx.x; rb * 64 < NN; rb += gridDim.x) {
    int r0 = rb * 64 + w * 16;
    int arow = min(r0 + l15, NN - 1);
    f32x4 acc[8] = {};
#pragma unroll
    for (int ks = 0; ks < 4; ++ks) {
      uint4 au = *(const uint4*)&Hb[arow * 64 + ks * 16 + kg];
      au.x &= ~(((au.x >> 15) & 0x10001u) * 0xFFFFu);  // packed relu
      au.y &= ~(((au.y >> 15) & 0x10001u) * 0xFFFFu);
      au.z &= ~(((au.z >> 15) & 0x10001u) * 0xFFFFu);
      au.w &= ~(((au.w >> 15) & 0x10001u) * 0xFFFFu);
      bf16x8 af = *(bf16x8*)&au;
#pragma unroll
      for (int nt = 0; nt < 8; ++nt) {
        uint4 bu = *(const uint4*)&WsL[(nt * 16 + l15) * 68 + ks * 16 + kg];
        bf16x8 bf = *(bf16x8*)&bu;
        acc[nt] = __builtin_amdgcn_mfma_f32_16x16x32_bf16(af, bf, acc[nt], 0, 0, 0);
      }
    }
#pragma unroll
    for (int nt = 0; nt < 8; ++nt) {
#pragma unroll
      for (int reg = 0; reg < 4; ++reg) {
        float v = acc[nt][reg] + bl[nt];
        float nb = __shfl_down(v, 1, 64);
        int rm = r0 + (l >> 4) * 4 + reg;
        if (((l & 1) == 0) && rm < NN)
          A[rm * 64 + nt * 8 + (l15 >> 1)] = pack2(v, nb);
      }
    }
  }
}

// ---- GATv2 edge phase v13: sorted nodes, 4 dst/wave, packed persistent state
//      (urx + att kept as bf16 pairs, unpacked per body w/ anti-hoist asm) ----

__global__ __launch_bounds__(256) void k_edge(const unsigned* __restrict__ XL,
    const unsigned* __restrict__ XR, const uint2* __restrict__ edat,
    const int* __restrict__ rowp, const int* __restrict__ ord,
    const float* __restrict__ We, const float* __restrict__ att,
    const float* __restrict__ bias, unsigned* __restrict__ Hb) {
  __shared__ float WeS[3 * HID];
  int t = threadIdx.x;
  for (int i = t; i < 3 * HID; i += 256) WeS[i] = We[i];
  __syncthreads();
  int lane = t & 63;
  int l4 = lane & 15;
  int n = blockIdx.x * 16 + (t >> 6) * 4 + (lane >> 4);  // sorted slot
  int orig = ord[n];
  int c0 = l4 * 8;
  uint4 urx = *(const uint4*)&XR[orig * 64 + l4 * 4];  // kept PACKED (4 regs)
  // att * log2e packed to bf16 pairs (4 regs)
  unsigned atp0, atp1, atp2, atp3;
  {
    f32x2 a01 = *(const f32x2*)&att[c0];
    f32x2 a23 = *(const f32x2*)&att[c0 + 2];
    f32x2 a45 = *(const f32x2*)&att[c0 + 4];
    f32x2 a67 = *(const f32x2*)&att[c0 + 6];
    atp0 = pack2(a01.x * 1.44269504f, a01.y * 1.44269504f);
    atp1 = pack2(a23.x * 1.44269504f, a23.y * 1.44269504f);
    atp2 = pack2(a45.x * 1.44269504f, a45.y * 1.44269504f);
    atp3 = pack2(a67.x * 1.44269504f, a67.y * 1.44269504f);
  }
  f32x2 w00 = *(const f32x2*)&WeS[c0],         w01 = *(const f32x2*)&WeS[c0 + 2];
  f32x2 w02 = *(const f32x2*)&WeS[c0 + 4],     w03 = *(const f32x2*)&WeS[c0 + 6];
  f32x2 w10 = *(const f32x2*)&WeS[HID + c0],   w11 = *(const f32x2*)&WeS[HID + c0 + 2];
  f32x2 w12 = *(const f32x2*)&WeS[HID + c0+4], w13 = *(const f32x2*)&WeS[HID + c0 + 6];
  f32x2 w20 = *(const f32x2*)&WeS[2*HID + c0],   w21 = *(const f32x2*)&WeS[2*HID + c0 + 2];
  f32x2 w22 = *(const f32x2*)&WeS[2*HID + c0+4], w23 = *(const f32x2*)&WeS[2*HID + c0 + 6];
  int beg = rowp[n], end = rowp[n + 1];
  int rem = end - beg;
  int tc = rem;
  tc = max(tc, __shfl_xor(tc, 16, 64));
  tc = max(tc, __shfl_xor(tc, 32, 64));
  int trips = (__builtin_amdgcn_readfirstlane(tc) + 3) & ~3;
  const unsigned* XLg = XL + l4 * 4;

  uint2 e0 = edat[beg], e1 = edat[beg + 1], e2 = edat[beg + 2], e3 = edat[beg + 3];
  uint4 x0 = *(const uint4*)&XLg[(e0.x & 0xffffu) * 64];
  uint4 x1;
  f32x2 a0 = {0.f, 0.f}, a1 = {0.f, 0.f}, a2 = {0.f, 0.f}, a3 = {0.f, 0.f};
  float s = 0.f;

#define BODY(ED, XU, J)                                                           \
  {                                                                               \
    /* anti-hoist: compiler must re-unpack per body (keeps state packed) */       \
    asm volatile("" : "+v"(urx.x), "+v"(urx.y), "+v"(urx.z), "+v"(urx.w),         \
                      "+v"(atp0), "+v"(atp1), "+v"(atp2), "+v"(atp3));            \
    f32x2 xr0 = {bf_lo(urx.x), bf_hi(urx.x)};                                     \
    f32x2 xr1 = {bf_lo(urx.y), bf_hi(urx.y)};                                     \
    f32x2 xr2 = {bf_lo(urx.z), bf_hi(urx.z)};                                     \
    f32x2 xr3 = {bf_lo(urx.w), bf_hi(urx.w)};                                     \
    f32x2 at0 = {bf_lo(atp0), bf_hi(atp0)};                                       \
    f32x2 at1 = {bf_lo(atp1), bf_hi(atp1)};                                       \
    f32x2 at2 = {bf_lo(atp2), bf_hi(atp2)};                                       \
    f32x2 at3 = {bf_lo(atp3), bf_hi(atp3)};                                       \
    f32x2 xs0 = {bf_lo(XU.x), bf_hi(XU.x)};                                       \
    f32x2 xs1 = {bf_lo(XU.y), bf_hi(XU.y)};                                       \
    f32x2 xs2 = {bf_lo(XU.z), bf_hi(XU.z)};                                       \
    f32x2 xs3 = {bf_lo(XU.w), bf_hi(XU.w)};                                       \
    float ea0 = bf_hi(ED.x), ea1 = bf_lo(ED.y), ea2 = bf_hi(ED.y);                \
    f32x2 u0 = xs0 + xr0, u1 = xs1 + xr1, u2 = xs2 + xr2, u3 = xs3 + xr3;         \
    u0 = ea0 * w00 + u0; u1 = ea0 * w01 + u1; u2 = ea0 * w02 + u2; u3 = ea0 * w03 + u3; \
    u0 = ea1 * w10 + u0; u1 = ea1 * w11 + u1; u2 = ea1 * w12 + u2; u3 = ea1 * w13 + u3; \
    u0 = ea2 * w20 + u0; u1 = ea2 * w21 + u1; u2 = ea2 * w22 + u2; u3 = ea2 * w23 + u3; \
    f32x2 v0 = __builtin_elementwise_max(u0, 0.2f * u0);                          \
    f32x2 v1 = __builtin_elementwise_max(u1, 0.2f * u1);                          \
    f32x2 v2 = __builtin_elementwise_max(u2, 0.2f * u2);                          \
    f32x2 v3 = __builtin_elementwise_max(u3, 0.2f * u3);                          \
    f32x2 pl = v0 * at0;                                                          \
    pl = v1 * at1 + pl;                                                           \
    pl = v2 * at2 + pl;                                                           \
    pl = v3 * at3 + pl;                                                           \
    float part = pl.x + pl.y;                                                     \
    DPPADD(part, 0x121, 0xf);  /* row_ror:1 */                                    \
    DPPADD(part, 0x122, 0xf);  /* row_ror:2 */                                    \
    DPPADD(part, 0x124, 0xf);  /* row_ror:4 */                                    \
    DPPADD(part, 0x128, 0xf);  /* row_ror:8 -> all 16 lanes hold node sum */      \
    float p = __builtin_amdgcn_exp2f(part);                                       \
    p = (i + (J) < rem) ? p : 0.f;                                                \
    s += p;                                                                       \
    a0 = p * xs0 + a0; a1 = p * xs1 + a1;                                         \
    a2 = p * xs2 + a2; a3 = p * xs3 + a3;                                         \
  }

  for (int i = 0; i < trips; i += 4) {
    x1 = *(const uint4*)&XLg[(e1.x & 0xffffu) * 64];
    BODY(e0, x0, 0);
    e0 = edat[beg + i + 4];
    x0 = *(const uint4*)&XLg[(e2.x & 0xffffu) * 64];
    BODY(e1, x1, 1);
    e1 = edat[beg + i + 5];
    x1 = *(const uint4*)&XLg[(e3.x & 0xffffu) * 64];
    BODY(e2, x0, 2);
    e2 = edat[beg + i + 6];
    x0 = *(const uint4*)&XLg[(e0.x & 0xffffu) * 64];
    BODY(e3, x1, 3);
    e3 = edat[beg + i + 7];
  }
#undef BODY

  float inv = 1.f / s;
  f32x2 b0 = *(const f32x2*)&bias[c0];
  f32x2 b1 = *(const f32x2*)&bias[c0 + 2];
  f32x2 b2 = *(const f32x2*)&bias[c0 + 4];
  f32x2 b3 = *(const f32x2*)&bias[c0 + 6];
  f32x2 o0 = a0 * inv + b0;
  f32x2 o1 = a1 * inv + b1;
  f32x2 o2 = a2 * inv + b2;
  f32x2 o3 = a3 * inv + b3;
  uint4 o;
  o.x = pack2(o0.x, o0.y);
  o.y = pack2(o1.x, o1.y);
  o.z = pack2(o2.x, o2.y);
  o.w = pack2(o3.x, o3.y);
  *(uint4*)&Hb[orig * 64 + l4 * 4] = o;
}

// ---------------- BN stats ----------------

__global__ __launch_bounds__(256) void k_bnstats(const unsigned* __restrict__ Hb,
                                                 float* __restrict__ cs) {
  __shared__ float red[8][256];
  int t = threadIdx.x;
  int ui = (t & 31) * 2;
  int c0 = ui * 2;
  int grp = t >> 5;
  int chunk = (NN + gridDim.x - 1) / gridDim.x;
  int n0 = blockIdx.x * chunk, n1 = min(n0 + chunk, NN);
  float s10 = 0.f, s11 = 0.f, s12 = 0.f, s13 = 0.f;
  float s20 = 0.f, s21 = 0.f, s22 = 0.f, s23 = 0.f;
  for (int n = n0 + grp; n < n1; n += 8) {
    uint2 h = *(const uint2*)&Hb[n * 64 + ui];
    float v0 = fmaxf(bf_lo(h.x), 0.f), v1 = fmaxf(bf_hi(h.x), 0.f);
    float v2 = fmaxf(bf_lo(h.y), 0.f), v3 = fmaxf(bf_hi(h.y), 0.f);
    s10 += v0; s11 += v1; s12 += v2; s13 += v3;
    s20 += v0 * v0; s21 += v1 * v1; s22 += v2 * v2; s23 += v3 * v3;
  }
  red[grp][c0 + 0] = s10; red[grp][c0 + 1] = s11;
  red[grp][c0 + 2] = s12; red[grp][c0 + 3] = s13;
  red[grp][128 + c0 + 0] = s20; red[grp][128 + c0 + 1] = s21;
  red[grp][128 + c0 + 2] = s22; red[grp][128 + c0 + 3] = s23;
  __syncthreads();
  float sum = 0.f;
#pragma unroll
  for (int g2 = 0; g2 < 8; ++g2) sum += red[g2][t];
  atomicAdd(&cs[t], sum);
}

// ---------------- pooling ----------------

__global__ __launch_bounds__(256) void k_pool(const unsigned* __restrict__ Hb,
    const int* __restrict__ batch, const float* __restrict__ cs,
    const float* __restrict__ g, const float* __restrict__ b,
    unsigned* __restrict__ pooled) {
  int t = threadIdx.x;
  int ui = (t & 31) * 2;
  int c0 = ui * 2;
  int grp = t >> 5;
  float scv0, scv1, scv2, scv3, shv0, shv1, shv2, shv3;
  {
    float mu, var;
    mu = cs[c0 + 0] * (1.f / NN); var = fmaxf(cs[HID + c0 + 0] * (1.f / NN) - mu * mu, 0.f);
    scv0 = g[c0 + 0] * rsqrtf(var + BNEPS); shv0 = b[c0 + 0] - mu * scv0;
    mu = cs[c0 + 1] * (1.f / NN); var = fmaxf(cs[HID + c0 + 1] * (1.f / NN) - mu * mu, 0.f);
    scv1 = g[c0 + 1] * rsqrtf(var + BNEPS); shv1 = b[c0 + 1] - mu * scv1;
    mu = cs[c0 + 2] * (1.f / NN); var = fmaxf(cs[HID + c0 + 2] * (1.f / NN) - mu * mu, 0.f);
    scv2 = g[c0 + 2] * rsqrtf(var + BNEPS); shv2 = b[c0 + 2] - mu * scv2;
    mu = cs[c0 + 3] * (1.f / NN); var = fmaxf(cs[HID + c0 + 3] * (1.f / NN) - mu * mu, 0.f);
    scv3 = g[c0 + 3] * rsqrtf(var + BNEPS); shv3 = b[c0 + 3] - mu * scv3;
  }
  int chunk = (NN + gridDim.x - 1) / gridDim.x;
  int n0 = blockIdx.x * chunk, n1 = min(n0 + chunk, NN);
  int curg = -1;
  float m0 = -3.402823e38f, m1 = m0, m2 = m0, m3 = m0;
  for (int n = n0 + grp; n < n1; n += 8) {
    int gg = batch[n];
    if (gg != curg) {
      if (curg >= 0) {
        atomicMax(&pooled[curg * HID + c0 + 0], fenc(m0));
        atomicMax(&pooled[curg * HID + c0 + 1], fenc(m1));
        atomicMax(&pooled[curg * HID + c0 + 2], fenc(m2));
        atomicMax(&pooled[curg * HID + c0 + 3], fenc(m3));
      }
      curg = gg;
      m0 = m1 = m2 = m3 = -3.402823e38f;
    }
    uint2 h = *(const uint2*)&Hb[n * 64 + ui];
    m0 = fmaxf(m0, fmaxf(bf_lo(h.x), 0.f) * scv0 + shv0);
    m1 = fmaxf(m1, fmaxf(bf_hi(h.x), 0.f) * scv1 + shv1);
    m2 = fmaxf(m2, fmaxf(bf_lo(h.y), 0.f) * scv2 + shv2);
    m3 = fmaxf(m3, fmaxf(bf_hi(h.y), 0.f) * scv3 + shv3);
  }
  if (curg >= 0) {
    atomicMax(&pooled[curg * HID + c0 + 0], fenc(m0));
    atomicMax(&pooled[curg * HID + c0 + 1], fenc(m1));
    atomicMax(&pooled[curg * HID + c0 + 2], fenc(m2));
    atomicMax(&pooled[curg * HID + c0 + 3], fenc(m3));
  }
}

// ---------------- FC head ----------------

__global__ __launch_bounds__(128) void k_fc(const unsigned* __restrict__ pooled,
    const float* __restrict__ W1, const float* __restrict__ b1,
    const float* __restrict__ W2, const float* __restrict__ b2,
    float* __restrict__ out) {
  __shared__ float P[HID];
  __shared__ float Z[HID];
  int g = blockIdx.x, c = threadIdx.x;
  unsigned k = pooled[g * HID + c];
  P[c] = (k & 0x80000000u) ? __uint_as_float(k ^ 0x80000000u) : __uint_as_float(~k);
  __syncthreads();
  float acc = b1[c];
  for (int kk = 0; kk < HID; ++kk) acc += P[kk] * W1[kk * HID + c];
  Z[c] = fmaxf(acc, 0.f);
  __syncthreads();
  if (c < 40) {
    float a2 = b2[c];
    for (int kk = 0; kk < HID; ++kk) a2 += Z[kk] * W2[kk * 40 + c];
    out[g * 40 + c] = a2;
  }
}

// ---------------- launch ----------------

extern "C" void kernel_launch(void* const* d_in, const int* in_sizes, int n_in,
                              void* d_out, int out_size, void* d_ws, size_t ws_size,
                              hipStream_t stream) {
  (void)in_sizes; (void)n_in; (void)out_size; (void)ws_size;
  const float* x     = (const float*)d_in[0];
  const float* eattr = (const float*)d_in[1];
  const int*   ei    = (const int*)d_in[2];
  const int*   batch = (const int*)d_in[3];
  const float* W0l   = (const float*)d_in[4];
  const float* W0r   = (const float*)d_in[5];
  const float* We0   = (const float*)d_in[6];
  const float* a0    = (const float*)d_in[7];
  const float* b0    = (const float*)d_in[8];
  const float* bn0g  = (const float*)d_in[9];
  const float* bn0b  = (const float*)d_in[10];
  const float* Wl    = (const float*)d_in[11];
  const float* Wel   = (const float*)d_in[12];
  const float* al    = (const float*)d_in[13];
  const float* bl    = (const float*)d_in[14];
  const float* bng   = (const float*)d_in[15];
  const float* bnb   = (const float*)d_in[16];
  const float* fc1W  = (const float*)d_in[17];
  const float* fc1b  = (const float*)d_in[18];
  const float* fc2W  = (const float*)d_in[19];
  const float* fc2b  = (const float*)d_in[20];
  float* out = (float*)d_out;

  char* ws = (char*)d_ws;
  unsigned* Hbf  = (unsigned*)(ws + 0);            // 12,800,000  (bf16 H)
  unsigned* Abf  = (unsigned*)(ws + 12800000);     // 12,800,000  (bf16 features)
  unsigned* X0bf = (unsigned*)(ws + 25600000);     // 12,800,000  (layer0 XR, bf16)
  uint2*    edat = (uint2*)(ws + 38400000);        // (850000+256)*8 = 6,802,048
  int*      rowp = (int*)(ws + 45202048);          // 50001*4
  int*      pos  = (int*)(ws + 45402112);          // 3,200,000
  unsigned* wtb   = (unsigned*)(ws + 48602112);    // 32,768
  float*    bias2 = (float*)(ws + 48634880);       // 512
  int*      ord  = (int*)(ws + 48635392);          // 200,000
  int*      rank = (int*)(ws + 48835392);          // 200,000
  int*      dbase = (int*)(ws + 49035392);         // 4,096
  char*     zb   = ws + 49039488;                  // zeroed region start
  int*      deg  = (int*)(zb + 0);                 // 200,000
  float*    cs   = (float*)(zb + 200000);          // 3,072
  unsigned* pooled = (unsigned*)(zb + 203072);     // 16,384
  int*      bsum = (int*)(zb + 219456);            // 256
  int*      dhist = (int*)(zb + 219712);           // 4,096
  int*      dfill = (int*)(zb + 223808);           // 4,096
  const size_t ZLEN = 227904;

  hipMemsetAsync(zb, 0, ZLEN, stream);

  // CSR build over degree-sorted node order (two-level histograms)
  k_hist<<<(NE + 255) / 256, 256, 0, stream>>>(ei, deg, pos);
  k_dhist<<<49, 1024, 0, stream>>>(deg, dhist);
  k_dscan<<<1, 1024, 0, stream>>>(dhist, dbase);
  k_dscatter<<<49, 1024, 0, stream>>>(deg, dbase, dfill, ord, rank);
  k_scanA<<<49, 1024, 0, stream>>>(deg, ord, rowp, bsum);
  k_scanB<<<1, 64, 0, stream>>>(bsum, rowp, edat);
  k_scanC<<<49, 1024, 0, stream>>>(rowp, bsum);
  k_scatter<<<(NE + 255) / 256, 256, 0, stream>>>(ei, eattr, rowp, pos, rank, edat);
  k_selfmean<<<(NN + 255) / 256, 256, 0, stream>>>(rowp, ord, edat);

  // layer 0
  k_xform0<<<(NN * 32) / 256, 256, 0, stream>>>(x, W0l, W0r, Abf, X0bf);
  k_edge<<<(NN + 15) / 16, 256, 0, stream>>>(Abf, X0bf, edat, rowp, ord, We0, a0, b0, Hbf);
  k_bnstats<<<512, 256, 0, stream>>>(Hbf, cs);

  // layer 1
  k_wprep<<<1, 256, 0, stream>>>(Wl, cs, bn0g, bn0b, wtb, bias2);
  k_gemm<<<391, 256, 0, stream>>>(Hbf, wtb, bias2, Abf);
  k_edge<<<(NN + 15) / 16, 256, 0, stream>>>(Abf, Abf, edat, rowp, ord, Wel, al, bl, Hbf);
  k_bnstats<<<512, 256, 0, stream>>>(Hbf, cs + 256);

  // layer 2
  k_wprep<<<1, 256, 0, stream>>>(Wl + 128 * 128, cs + 256, bng, bnb, wtb, bias2);
  k_gemm<<<391, 256, 0, stream>>>(Hbf, wtb, bias2, Abf);
  k_edge<<<(NN + 15) / 16, 256, 0, stream>>>(Abf, Abf, edat, rowp, ord, Wel + 384, al + 128, bl + 128, Hbf);
  k_bnstats<<<512, 256, 0, stream>>>(Hbf, cs + 512);

  // pool + FC head
  k_pool<<<512, 256, 0, stream>>>(Hbf, batch, cs + 512, bng + 128, bnb + 128, pooled);
  k_fc<<<NG, 128, 0, stream>>>(pooled, fc1W, fc1b, fc2W, fc2b, out);
}